// Round 1
// baseline (88.307 us; speedup 1.0000x reference)
//
#include <hip/hip_runtime.h>

#define Bb 4
#define AT 384
#define NBR 24
#define FEAT 128

// One block per (b, a, j). Computes the 24-entry match mask in LDS, then
// streams the masked copy of edge_embedding[b,a,:,:] (24x128 floats) to
// out[b,a,j,:,:] with coalesced float4 stores.
__global__ __launch_bounds__(256) void GetEdgeJK_kernel(
    const float* __restrict__ edge,   // (B, AT, NBR, FEAT)
    const int*   __restrict__ nbr,    // (B, AT, NBR)
    const float* __restrict__ cell,   // (B, AT, NBR, 3)
    float*       __restrict__ out)    // (B, AT, NBR_j, NBR_i, FEAT)
{
    const int blk = blockIdx.x;        // (b*AT + a)*NBR + j
    const int j   = blk % NBR;
    const int ba  = blk / NBR;         // b*AT + a
    const int b   = ba / AT;

    __shared__ int   s_nbrj[NBR];
    __shared__ float s_cellj[NBR][3];
    __shared__ int   s_mask[NBR];

    const int t = threadIdx.x;

    // atom index of the j-th neighbor of atom (b,a)
    const int jatom = nbr[ba * NBR + j];

    // stage neighbors-of-j (index + cell offset) into LDS
    if (t < NBR) {
        const int base = (b * AT + jatom) * NBR + t;
        s_nbrj[t]     = nbr[base];
        s_cellj[t][0] = cell[base * 3 + 0];
        s_cellj[t][1] = cell[base * 3 + 1];
        s_cellj[t][2] = cell[base * 3 + 2];
    }
    __syncthreads();

    // mask[i] = (i != j) && exists k: nbr[b,jatom,k]==nbr[b,a,i]
    //                              && cell[b,jatom,k,:] == cell[b,a,i,:]
    if (t < NBR) {
        const int i = t;
        int m = 0;
        if (i != j) {
            const int   myidx = nbr[ba * NBR + i];
            const float c0 = cell[(ba * NBR + i) * 3 + 0];
            const float c1 = cell[(ba * NBR + i) * 3 + 1];
            const float c2 = cell[(ba * NBR + i) * 3 + 2];
            #pragma unroll
            for (int k = 0; k < NBR; ++k) {
                if (s_nbrj[k] == myidx &&
                    s_cellj[k][0] == c0 &&
                    s_cellj[k][1] == c1 &&
                    s_cellj[k][2] == c2) { m = 1; }
            }
        }
        s_mask[i] = m;
    }
    __syncthreads();

    // Write NBR*FEAT = 3072 floats = 768 float4 per block.
    const float4* __restrict__ erow = (const float4*)(edge + (size_t)ba * NBR * FEAT);
    float4*       __restrict__ orow = (float4*)(out + (size_t)blk * NBR * FEAT);

    const float4 zero = make_float4(0.f, 0.f, 0.f, 0.f);
    #pragma unroll
    for (int it = 0; it < 3; ++it) {
        const int q = t + it * 256;    // float4 index in [0, 768)
        const int i = q >> 5;          // which neighbor row (128 floats = 32 float4)
        float4 v = zero;
        if (s_mask[i]) v = erow[q];    // uniform across each 32-thread subgroup
        orow[q] = v;
    }
}

extern "C" void kernel_launch(void* const* d_in, const int* in_sizes, int n_in,
                              void* d_out, int out_size, void* d_ws, size_t ws_size,
                              hipStream_t stream) {
    const float* edge = (const float*)d_in[0];
    const int*   nbr  = (const int*)d_in[1];
    const float* cell = (const float*)d_in[2];
    float*       out  = (float*)d_out;

    const int nblocks = Bb * AT * NBR;   // 36864
    GetEdgeJK_kernel<<<nblocks, 256, 0, stream>>>(edge, nbr, cell, out);
}